// Round 4
// baseline (501.322 us; speedup 1.0000x reference)
//
#include <hip/hip_runtime.h>

// CRF forward scan in LINEAR space, one wave per chain, no barriers.
// R4 vs R3: recurrence V(t+1) = exp(h_t) ⊙ (E·V(t)) * F with power-of-2
// rescale F and integer log2-scale accumulator (exact). Removes per-step
// log/exp/max from the serial critical path:
//   - exp(h) depends only on prefetched h  -> overlapped with the dot
//   - log is gone (only k += e7 int add; logs return in the epilogue)
//   - max-reduce (normalization only) uses the PREVIOUS V, runs
//     concurrently with the next step's dot -> off-path
// Critical path/step ~= ds_read latency + 128 dot2 issue + 2 mul + cvt +
// ds_write ~= 400cy (was ~1130cy).
// f16 range audit: max V normalized to ~2^-7; worst one-step growth
// <= 128*e^{maxE}*e^{maxh} ~= e^{14.9}; overflow needs e^{15.2}. Safe.

typedef _Float16 h2 __attribute__((ext_vector_type(2)));

static constexpr int BB = 256, SS = 1024, TT = 128, HCH = 8;
#define LN2F 0.69314718056f

__device__ __forceinline__ float dot2f(h2 a, h2 b, float c) {
    return __builtin_amdgcn_fdot2(a, b, c, false);
}

// Full-wave (64-lane) max via DPP; result uniform via readlane(63).
__device__ __forceinline__ float wave_max_dpp(float v) {
    int x, y;
    x = __builtin_bit_cast(int, v);
    y = __builtin_amdgcn_update_dpp(x, x, 0xB1, 0xF, 0xF, false);   // quad_perm [1,0,3,2]
    v = fmaxf(v, __builtin_bit_cast(float, y));
    x = __builtin_bit_cast(int, v);
    y = __builtin_amdgcn_update_dpp(x, x, 0x4E, 0xF, 0xF, false);   // quad_perm [2,3,0,1]
    v = fmaxf(v, __builtin_bit_cast(float, y));
    x = __builtin_bit_cast(int, v);
    y = __builtin_amdgcn_update_dpp(x, x, 0x141, 0xF, 0xF, false);  // row_half_mirror
    v = fmaxf(v, __builtin_bit_cast(float, y));
    x = __builtin_bit_cast(int, v);
    y = __builtin_amdgcn_update_dpp(x, x, 0x140, 0xF, 0xF, false);  // row_mirror
    v = fmaxf(v, __builtin_bit_cast(float, y));
    x = __builtin_bit_cast(int, v);
    y = __builtin_amdgcn_update_dpp(x, x, 0x142, 0xA, 0xF, false);  // row_bcast15
    v = fmaxf(v, __builtin_bit_cast(float, y));
    x = __builtin_bit_cast(int, v);
    y = __builtin_amdgcn_update_dpp(x, x, 0x143, 0xC, 0xF, false);  // row_bcast31
    v = fmaxf(v, __builtin_bit_cast(float, y));
    return __builtin_bit_cast(float,
        __builtin_amdgcn_readlane(__builtin_bit_cast(int, v), 63));
}

__global__ __launch_bounds__(64, 1) void crf_lin_kernel(
        const float* __restrict__ h, const float* __restrict__ mask,
        const float* __restrict__ trans, float* __restrict__ out) {
    const int b = blockIdx.x;
    const int l = threadIdx.x;          // 0..63
    const int i0 = 2 * l, i1 = i0 + 1;  // owned states

    __shared__ alignas(16) unsigned V2[64];   // packed f16x2 state vector

    // ---- one-time: E rows i0,i1 = exp(trans[row,:]) as 64 packed f16x2 each
    h2 E0[64], E1[64];
    {
        const float4* r0 = reinterpret_cast<const float4*>(trans + (size_t)i0 * TT);
        const float4* r1 = reinterpret_cast<const float4*>(trans + (size_t)i1 * TT);
        #pragma unroll
        for (int q = 0; q < 32; ++q) {
            float4 a = r0[q], c = r1[q];
            E0[2*q]   = h2{(_Float16)__expf(a.x), (_Float16)__expf(a.y)};
            E0[2*q+1] = h2{(_Float16)__expf(a.z), (_Float16)__expf(a.w)};
            E1[2*q]   = h2{(_Float16)__expf(c.x), (_Float16)__expf(c.y)};
            E1[2*q+1] = h2{(_Float16)__expf(c.z), (_Float16)__expf(c.w)};
        }
    }

    // ---- len = sum(mask[b,:]) (mask monotone)
    const float* mrow = mask + (size_t)b * SS;
    float cnt = 0.f;
    #pragma unroll
    for (int t = 0; t < SS / 64; ++t) cnt += mrow[t * 64 + l];
    #pragma unroll
    for (int o = 32; o; o >>= 1) cnt += __shfl_xor(cnt, o, 64);
    const int len = (int)(cnt + 0.5f);

    // ---- init: V(0) = exp(score0): 2^-7 at SOS (pre-scaled), 0 elsewhere.
    // L(0) = 7*ln2  ->  kacc = 7.
    V2[l] = (l == 0) ? 0x00002000u : 0u;      // f16 {2^-7, 0}
    asm volatile("" ::: "memory");
    int   kacc = 7;
    float F    = 1.0f;   int e7F = 0;          // factor applied THIS step
    float sv0  = (l == 0) ? 0.0078125f : 0.0f, sv1 = 0.0f;  // last committed V

    const float* hb = h + ((size_t)b * SS) * TT + i0;

    auto load_chunk = [&](float2* buf, int tbase) {
        #pragma unroll
        for (int k = 0; k < HCH; ++k) {
            int t = tbase + k; t = (t < SS) ? t : (SS - 1);
            buf[k] = *reinterpret_cast<const float2*>(hb + (size_t)t * TT);
        }
    };

    auto step = [&](float2 hk, int t) {
        // off-path: exp(h) (depends only on prefetched regs)
        float eh0 = __expf(hk.x), eh1 = __expf(hk.y);
        // dot: u = E · V  (broadcast b128 reads, f32 accum via dot2)
        const uint4* pv = reinterpret_cast<const uint4*>(V2);
        float a0=0,a1=0,a2=0,a3=0, c0=0,c1=0,c2=0,c3=0;
        #pragma unroll
        for (int q = 0; q < 16; ++q) {
            uint4 v = pv[q];
            h2 px = __builtin_bit_cast(h2, v.x);
            h2 py = __builtin_bit_cast(h2, v.y);
            h2 pz = __builtin_bit_cast(h2, v.z);
            h2 pw = __builtin_bit_cast(h2, v.w);
            a0 = dot2f(E0[4*q+0], px, a0);
            a1 = dot2f(E0[4*q+1], py, a1);
            a2 = dot2f(E0[4*q+2], pz, a2);
            a3 = dot2f(E0[4*q+3], pw, a3);
            c0 = dot2f(E1[4*q+0], px, c0);
            c1 = dot2f(E1[4*q+1], py, c1);
            c2 = dot2f(E1[4*q+2], pz, c2);
            c3 = dot2f(E1[4*q+3], pw, c3);
        }
        float u0 = (a0 + a1) + (a2 + a3);
        float u1 = (c0 + c1) + (c2 + c3);
        // scale (F is a power of 2: exact) and publish
        float V0 = u0 * eh0 * F;
        float V1 = u1 * eh1 * F;
        h2 pp = h2{(_Float16)V0, (_Float16)V1};
        const bool live = (t < len);               // wave-uniform
        if (live) V2[l] = __builtin_bit_cast(unsigned, pp);
        asm volatile("" ::: "memory");             // same-wave DS ops in-order
        // off-path: normalization factor for the NEXT step from this V
        float w = wave_max_dpp(fmaxf(V0, V1));
        unsigned wb = __builtin_bit_cast(unsigned, w);
        int Eb  = (int)((wb >> 23) & 0xffu) + (int)((wb >> 22) & 1u);
        int e7n = Eb - 120;                        // (Eb-127)+7
        float Fn = __builtin_bit_cast(float, (unsigned)(127 - e7n) << 23);
        if (live) { sv0 = V0; sv1 = V1; kacc += e7F; F = Fn; e7F = e7n; }
    };

    // ---- main scan: h double-buffered one chunk ahead
    float2 hA[HCH], hB[HCH];
    load_chunk(hA, 0);
    for (int t0 = 0; t0 < len; t0 += 2 * HCH) {
        load_chunk(hB, t0 + HCH);
        #pragma unroll
        for (int k = 0; k < HCH; ++k) step(hA[k], t0 + k);
        load_chunk(hA, t0 + 2 * HCH);
        #pragma unroll
        for (int k = 0; k < HCH; ++k) step(hB[k], t0 + HCH + k);
    }

    // ---- epilogue: s_i = log(V_i) + kacc*ln2 ; out = logsumexp(s + trans[EOS,:])
    const float base = (float)kacc * LN2F;
    float v0 = __logf(sv0) + base + trans[1 * TT + i0];   // log(0) = -inf: dead states
    float v1 = __logf(sv1) + base + trans[1 * TT + i1];
    float mm = fmaxf(v0, v1);
    #pragma unroll
    for (int o = 32; o; o >>= 1) mm = fmaxf(mm, __shfl_xor(mm, o, 64));
    float e = __expf(v0 - mm) + __expf(v1 - mm);
    #pragma unroll
    for (int o = 32; o; o >>= 1) e += __shfl_xor(e, o, 64);
    if (l == 0) out[b] = mm + __logf(e);
}

extern "C" void kernel_launch(void* const* d_in, const int* in_sizes, int n_in,
                              void* d_out, int out_size, void* d_ws, size_t ws_size,
                              hipStream_t stream) {
    const float* h     = (const float*)d_in[0];
    const float* mask  = (const float*)d_in[1];
    const float* trans = (const float*)d_in[2];
    float* out         = (float*)d_out;
    crf_lin_kernel<<<dim3(BB), dim3(64), 0, stream>>>(h, mask, trans, out);
}